// Round 4
// baseline (15007.430 us; speedup 1.0000x reference)
//
#include <hip/hip_runtime.h>
#include <hip/hip_fp16.h>
#include <math.h>

// Persistent-kernel greedy transformer decoder for MI355X (gfx950).
// B=8, D=512, NH=8 (hd=64), H=2048, NL=2, V=32000, L=48 steps.
// 256 blocks x 1024 threads (16 waves/CU). Grid barrier = relaxed agent atomics.
// Round-4 = round-3 with nontemporal builtins fixed to use ext_vector_type
// (HIP float4/uint4 wrappers are rejected by __builtin_nontemporal_*).

#define NBK 256
#define NTH 1024
#define NGRP 64

typedef float f4v __attribute__((ext_vector_type(4)));
typedef unsigned int u4v __attribute__((ext_vector_type(4)));

__device__ __forceinline__ float4 ntload4(const float* p) {
  const f4v x = __builtin_nontemporal_load((const f4v*)p);
  return make_float4(x.x, x.y, x.z, x.w);
}

namespace cfg {
constexpr int D = 512, HF = 2048, V = 32000, SM = 64;
constexpr float EPS = 1e-5f;
constexpr float PE_NEG = -0.017988946039015984f;  // -ln(10000)/512
constexpr float DELTA = 0.03f;                    // >> fp16 logit err bound (~0.004)

// workspace float offsets; [0..1023] zeroed by host memset (barrier + slots)
constexpr size_t O_SLOT = 768;                    // u64 slot[2][8] (32 floats)
constexpr size_t O_CAV  = 1024;
constexpr size_t O_CAC  = O_CAV + 8192;
constexpr size_t O_Q    = O_CAC + 8192;
constexpr size_t O_ATT  = O_Q + 4096;
constexpr size_t O_Y1   = O_ATT + 4096;
constexpr size_t O_Y2   = O_Y1 + 4096;
constexpr size_t O_HFF  = O_Y2 + 4096;
constexpr size_t O_CAND = O_HFF + 16384;
constexpr size_t O_KC   = O_CAND + (size_t)NBK * 8 * 2;
constexpr size_t O_VC   = O_KC + (size_t)2 * 8 * SM * 512;
constexpr size_t O_W16  = O_VC + (size_t)2 * 8 * SM * 512;
constexpr size_t WS_NEED16 = (O_W16 + (size_t)V * D / 2) * 4;
}

__device__ __forceinline__ float ld_dev(const float* p) {
  return __hip_atomic_load(p, __ATOMIC_RELAXED, __HIP_MEMORY_SCOPE_AGENT);
}
__device__ __forceinline__ void st_dev(float* p, float v) {
  __hip_atomic_store(p, v, __ATOMIC_RELAXED, __HIP_MEMORY_SCOPE_AGENT);
}
union F2U { float2 f; unsigned long long u; };
__device__ __forceinline__ float2 ld_dev2(const float* p) {
  F2U x; x.u = __hip_atomic_load((const unsigned long long*)p, __ATOMIC_RELAXED, __HIP_MEMORY_SCOPE_AGENT);
  return x.f;
}
__device__ __forceinline__ void st_dev2(float* p, float2 v) {
  F2U x; x.f = v;
  __hip_atomic_store((unsigned long long*)p, x.u, __ATOMIC_RELAXED, __HIP_MEMORY_SCOPE_AGENT);
}

// monotone float->u32 + inverted index => u64 atomicMax == argmax w/ first-max ties
__device__ __forceinline__ unsigned long long packkey(float v, int r) {
  unsigned u = __float_as_uint(v);
  u = (u & 0x80000000u) ? ~u : (u | 0x80000000u);
  return ((unsigned long long)u << 32) | (unsigned)(0x7FFFFFFF - r);
}

// GEMV: rows r = blockIdx.x*RPB + i (contiguous per block), K=512, 8 batches.
template <int RPB, bool NT, typename EPI>
__device__ __forceinline__ void gemv512n(const float* __restrict__ W,
                                         const float* __restrict__ bias,
                                         const float* xs, EPI&& epi) {
  const int tid = threadIdx.x, gl = tid & 15, grp = tid >> 4;
  for (int i = grp; i < RPB; i += NGRP) {
    const int r = blockIdx.x * RPB + i;
    const float* wr = W + (size_t)r * 512;
    float acc[8] = {0.f, 0.f, 0.f, 0.f, 0.f, 0.f, 0.f, 0.f};
#pragma unroll
    for (int ii = 0; ii < 8; ++ii) {
      const float4 wv = NT ? ntload4(wr + 4 * (gl + 16 * ii))
                           : ((const float4*)wr)[gl + 16 * ii];
#pragma unroll
      for (int b = 0; b < 8; ++b) {
        const float4 a = ((const float4*)(xs + b * 512))[gl + 16 * ii];
        acc[b] = fmaf(wv.x, a.x, acc[b]);
        acc[b] = fmaf(wv.y, a.y, acc[b]);
        acc[b] = fmaf(wv.z, a.z, acc[b]);
        acc[b] = fmaf(wv.w, a.w, acc[b]);
      }
    }
#pragma unroll
    for (int b = 0; b < 8; ++b) {
      float v = acc[b];
      v += __shfl_xor(v, 1); v += __shfl_xor(v, 2);
      v += __shfl_xor(v, 4); v += __shfl_xor(v, 8);
      acc[b] = v;
    }
    if (gl < 8) epi(gl, r, acc[gl] + bias[r]);
  }
}

__launch_bounds__(NTH)
__global__ void decoder_persistent(
    const float* __restrict__ memory, const float* __restrict__ embedding,
    const float* __restrict__ sa_in_w, const float* __restrict__ sa_in_b,
    const float* __restrict__ sa_out_w, const float* __restrict__ sa_out_b,
    const float* __restrict__ ca_in_w, const float* __restrict__ ca_in_b,
    const float* __restrict__ ca_out_w, const float* __restrict__ ca_out_b,
    const float* __restrict__ ff1_w, const float* __restrict__ ff1_b,
    const float* __restrict__ ff2_w, const float* __restrict__ ff2_b,
    const float* __restrict__ ln1_g, const float* __restrict__ ln1_b,
    const float* __restrict__ ln2_g, const float* __restrict__ ln2_b,
    const float* __restrict__ ln3_g, const float* __restrict__ ln3_b,
    const float* __restrict__ out_w, const float* __restrict__ out_b,
    const int* __restrict__ max_len_p,
    float* __restrict__ dout, float* __restrict__ wsf, int use16) {
  using namespace cfg;
  __shared__ __align__(16) float xs[8192];   // 32 KB staging
  __shared__ float2 gcand[NGRP * 8];
  __shared__ float gapx[8];
  __shared__ int tok_ls[8];
  __shared__ int qn;
  __shared__ int qlist[128];

  const int tid  = threadIdx.x;
  const int w    = tid >> 6;    // wave id; waves 0..7 own batch rows for LN
  const int lane = tid & 63;
  const int col0 = lane * 8;
  const int bid  = blockIdx.x;
  const int L = max_len_p[0];

  unsigned* bcnt = (unsigned*)wsf;           // 16 sub-counters, 128B apart
  unsigned* bmaster = (unsigned*)wsf + 512;
  unsigned* bgen = (unsigned*)wsf + 544;
  unsigned long long* slot = (unsigned long long*)(wsf + O_SLOT);  // [2][8]
  unsigned nbar = 0;

  float* cav  = wsf + O_CAV;
  float* cac  = wsf + O_CAC;
  float* qb   = wsf + O_Q;
  float* attn = wsf + O_ATT;
  float* y1   = wsf + O_Y1;
  float* y2   = wsf + O_Y2;
  float* hff  = wsf + O_HFF;
  float* cand = wsf + O_CAND;               // float2[256][8]
  float* kc   = wsf + O_KC;
  float* vc   = wsf + O_VC;
  __half* w16 = (__half*)(wsf + O_W16);
  float* dlog = dout + (size_t)8 * L;

  float x0r[8];   // layer input row w (residual for LN1) — waves 0..7
  float x2r[8];   // LN2 output row w (residual for LN3) — waves 0..7

  auto gsync = [&]() {
    __syncthreads();
    if (tid == 0) {
      ++nbar;
      const unsigned sg = (unsigned)bid & 15u;
      unsigned old = __hip_atomic_fetch_add(&bcnt[sg * 32], 1u,
                                            __ATOMIC_RELAXED, __HIP_MEMORY_SCOPE_AGENT);
      if ((old & 15u) == 15u) {
        unsigned old2 = __hip_atomic_fetch_add(bmaster, 1u,
                                               __ATOMIC_RELAXED, __HIP_MEMORY_SCOPE_AGENT);
        if ((old2 & 15u) == 15u)
          __hip_atomic_store(bgen, nbar, __ATOMIC_RELAXED, __HIP_MEMORY_SCOPE_AGENT);
      }
      while (__hip_atomic_load(bgen, __ATOMIC_RELAXED, __HIP_MEMORY_SCOPE_AGENT) < nbar)
        __builtin_amdgcn_s_sleep(1);
    }
    __syncthreads();
  };

  auto wave_ln = [&](float (&v)[8], const float* g, const float* bta) {
    float s = 0.f, s2 = 0.f;
#pragma unroll
    for (int j = 0; j < 8; ++j) { s += v[j]; s2 = fmaf(v[j], v[j], s2); }
#pragma unroll
    for (int m = 1; m < 64; m <<= 1) { s += __shfl_xor(s, m); s2 += __shfl_xor(s2, m); }
    const float mean = s * (1.f / 512.f);
    const float var  = s2 * (1.f / 512.f) - mean * mean;
    const float inv  = 1.0f / sqrtf(var + EPS);
    const float4 g0 = ((const float4*)(g + col0))[0], g1 = ((const float4*)(g + col0))[1];
    const float4 b0 = ((const float4*)(bta + col0))[0], b1 = ((const float4*)(bta + col0))[1];
    const float gg[8] = {g0.x, g0.y, g0.z, g0.w, g1.x, g1.y, g1.z, g1.w};
    const float bb[8] = {b0.x, b0.y, b0.z, b0.w, b1.x, b1.y, b1.z, b1.w};
#pragma unroll
    for (int j = 0; j < 8; ++j) v[j] = (v[j] - mean) * inv * gg[j] + bb[j];
  };

  // ============ init A: out_w -> fp16, lane-permuted rows ============
  // stored half p = gl*32 + j  <->  original k = gl*4 + (j&3) + 64*(j>>2)
  if (use16) {
    const size_t total8 = (size_t)V * D / 8;  // 16B units
    for (size_t u = (size_t)bid * NTH + tid; u < total8; u += (size_t)NBK * NTH) {
      const size_t p0 = u * 8;
      const size_t r = p0 >> 9;
      const int pr = (int)(p0 & 511);
      const int gl = pr >> 5, i0 = (pr & 31) >> 2;  // i0 in {0,2,4,6}
      const float* src = out_w + r * 512 + gl * 4;
      const float4 a0 = ntload4(src + 64 * i0);
      const float4 a1 = ntload4(src + 64 * (i0 + 1));
      __half2 h0 = __float22half2_rn(make_float2(a0.x, a0.y));
      __half2 h1 = __float22half2_rn(make_float2(a0.z, a0.w));
      __half2 h2 = __float22half2_rn(make_float2(a1.x, a1.y));
      __half2 h3 = __float22half2_rn(make_float2(a1.z, a1.w));
      u4v pk;
      pk.x = *(const unsigned*)&h0; pk.y = *(const unsigned*)&h1;
      pk.z = *(const unsigned*)&h2; pk.w = *(const unsigned*)&h3;
      __builtin_nontemporal_store(pk, (u4v*)w16 + u);
    }
  }
  // ============ init B: cross-attn constant ============
  {
    const int gtid = bid * NTH + tid;
    if (gtid < 2 * 8 * 512) {
      const int b = gtid & 7, r = (gtid >> 3) & 511, l = gtid >> 12;
      const float4* a4 = (const float4*)(memory + (size_t)b * 512);
      const float4* w4 = (const float4*)(ca_in_w + ((size_t)l * 1536 + 1024 + r) * 512);
      float s = 0.f;
      for (int i = 0; i < 128; ++i) {
        const float4 a = a4[i], ww = w4[i];
        s = fmaf(a.x, ww.x, s); s = fmaf(a.y, ww.y, s);
        s = fmaf(a.z, ww.z, s); s = fmaf(a.w, ww.w, s);
      }
      st_dev(&cav[((size_t)l * 8 + b) * 512 + r], s + ca_in_b[l * 1536 + 1024 + r]);
    }
  }
  gsync();
  {
    const int gtid = bid * NTH + tid;
    if (gtid < 2 * 8 * 512) {
      const int b = gtid & 7, r = (gtid >> 3) & 511, l = gtid >> 12;
      const float* a = cav + ((size_t)l * 8 + b) * 512;
      const float4* w4 = (const float4*)(ca_out_w + ((size_t)l * 512 + r) * 512);
      float s = 0.f;
      for (int i = 0; i < 128; ++i) {
        const float4 ww = w4[i];
        s = fmaf(ld_dev(a + 4 * i + 0), ww.x, s);
        s = fmaf(ld_dev(a + 4 * i + 1), ww.y, s);
        s = fmaf(ld_dev(a + 4 * i + 2), ww.z, s);
        s = fmaf(ld_dev(a + 4 * i + 3), ww.w, s);
      }
      st_dev(&cac[((size_t)l * 8 + b) * 512 + r], s + ca_out_b[l * 512 + r]);
    }
  }
  gsync();

  // ================= autoregressive decode =================
  for (int t = 0; t < L; ++t) {
    const int p = t & 1;
    for (int l = 0; l < 2; ++l) {
      // ---------- build layer input rows into xs (+ x0r regs) ----------
      if (l == 0) {
        if (t > 0) {
          if (tid < 8) {
            const unsigned long long key =
                __hip_atomic_load(&slot[(size_t)(1 - p) * 8 + tid],
                                  __ATOMIC_RELAXED, __HIP_MEMORY_SCOPE_AGENT);
            const int idx = 0x7FFFFFFF - (int)(unsigned)(key & 0xFFFFFFFFull);
            tok_ls[tid] = idx;
            if (bid == 0) dout[(size_t)tid * L + (t - 1)] = (float)idx;
          }
        } else {
          if (tid < 8) tok_ls[tid] = 1;  // SOS
        }
        __syncthreads();
        if (w < 8) {
          const int tok = tok_ls[w];
          const float4* e4 = (const float4*)(embedding + (size_t)tok * 512 + col0);
          const float4 e0 = e4[0], e1 = e4[1];
          float v[8] = {e0.x, e0.y, e0.z, e0.w, e1.x, e1.y, e1.z, e1.w};
#pragma unroll
          for (int j = 0; j < 8; ++j) {
            const int c = col0 + j;
            const float ang = (float)t * expf((float)(c & ~1) * PE_NEG);
            v[j] += (c & 1) ? cosf(ang) : sinf(ang);
            x0r[j] = v[j];
            xs[w * 512 + c] = v[j];
          }
        }
        __syncthreads();
      } else {
        if (w < 8) {
          float v[8];
#pragma unroll
          for (int j2 = 0; j2 < 4; ++j2) {
            const float2 yv = ld_dev2(y2 + (size_t)w * 512 + col0 + 2 * j2);
            v[2 * j2] = x2r[2 * j2] + yv.x;
            v[2 * j2 + 1] = x2r[2 * j2 + 1] + yv.y;
          }
          wave_ln(v, ln3_g, ln3_b);  // layer-0 LN3
#pragma unroll
          for (int j = 0; j < 8; ++j) { x0r[j] = v[j]; xs[w * 512 + col0 + j] = v[j]; }
        }
        __syncthreads();
      }

      // ---------- QKV GEMV (full grid, 6 rows/block) ----------
      gemv512n<6, false>(sa_in_w + (size_t)l * 1536 * 512, sa_in_b + l * 1536, xs,
              [&](int b, int r, float val) {
                if (r < 512) st_dev(&qb[(size_t)b * 512 + r], val);
                else if (r < 1024) st_dev(&kc[(((size_t)l * 8 + b) * SM + t) * 512 + (r - 512)], val);
                else st_dev(&vc[(((size_t)l * 8 + b) * SM + t) * 512 + (r - 1024)], val);
              });
      gsync();

      // ---------- self-attention: blocks 0..7 (block=batch, wave=head) ----
      if (bid < 8) {
        const int b = bid, h = w;
        float* q_l = xs + (h & 7) * 128;
        float* p_l = q_l + 64;
        const float* kcb = kc + ((size_t)(l * 8 + b) * SM) * 512 + (h & 7) * 64;
        const float* vcb = vc + ((size_t)(l * 8 + b) * SM) * 512 + (h & 7) * 64;
        if (h < 8) q_l[lane] = ld_dev(qb + (size_t)b * 512 + h * 64 + lane);
        __syncthreads();
        if (h < 8 && lane <= t) {
          float s = 0.f;
          if (lane < t) {
            const float4* k4 = (const float4*)(kcb + (size_t)lane * 512);
            const float4* q4 = (const float4*)q_l;
#pragma unroll
            for (int i = 0; i < 16; ++i) {
              const float4 kk = k4[i], qq = q4[i];
              s = fmaf(kk.x, qq.x, s); s = fmaf(kk.y, qq.y, s);
              s = fmaf(kk.z, qq.z, s); s = fmaf(kk.w, qq.w, s);
            }
          } else {
            for (int i = 0; i < 64; ++i)
              s = fmaf(ld_dev(kcb + (size_t)lane * 512 + i), q_l[i], s);
          }
          p_l[lane] = s * 0.125f;
        }
        __syncthreads();
        float mx = -3.4e38f;
        if (h < 8) for (int k = 0; k <= t; ++k) mx = fmaxf(mx, p_l[k]);
        __syncthreads();
        if (h < 8 && lane <= t) p_l[lane] = expf(p_l[lane] - mx);
        __syncthreads();
        if (h < 8) {
          float den = 0.f, o = 0.f;
          for (int k = 0; k <= t; ++k) {
            const float pp = p_l[k];
            const float vv = (k < t) ? vcb[(size_t)k * 512 + lane]
                                     : ld_dev(vcb + (size_t)k * 512 + lane);
            den += pp;
            o = fmaf(pp, vv, o);
          }
          st_dev(&attn[(size_t)b * 512 + h * 64 + lane], o / den);
        }
      }
      gsync();

      // ---------- attention out-proj (blocks 0..63, 8 rows each) ----------
      if (bid < 64) {
        for (int j2 = tid; j2 < 2048; j2 += NTH)
          ((float2*)xs)[j2] = ld_dev2(attn + 2 * j2);
        __syncthreads();
        gemv512n<8, false>(sa_out_w + (size_t)l * 512 * 512, sa_out_b + l * 512, xs,
                [&](int b, int r, float val) { st_dev(&y1[(size_t)b * 512 + r], val); });
      }
      gsync();

      // ---------- LN1 + ca_const + LN2 (regs) then FF1 (full grid) ----------
      if (w < 8) {
        float v[8];
#pragma unroll
        for (int j2 = 0; j2 < 4; ++j2) {
          const float2 yv = ld_dev2(y1 + (size_t)w * 512 + col0 + 2 * j2);
          v[2 * j2] = x0r[2 * j2] + yv.x;
          v[2 * j2 + 1] = x0r[2 * j2 + 1] + yv.y;
        }
        wave_ln(v, ln1_g + l * 512, ln1_b + l * 512);
        const float4* c4 = (const float4*)(cac + ((size_t)l * 8 + w) * 512 + col0);
        const float4 c0 = c4[0], c1 = c4[1];   // immutable after init: cached
        const float cc[8] = {c0.x, c0.y, c0.z, c0.w, c1.x, c1.y, c1.z, c1.w};
#pragma unroll
        for (int j = 0; j < 8; ++j) v[j] += cc[j];
        wave_ln(v, ln2_g + l * 512, ln2_b + l * 512);
#pragma unroll
        for (int j = 0; j < 8; ++j) { x2r[j] = v[j]; xs[w * 512 + col0 + j] = v[j]; }
      }
      __syncthreads();
      gemv512n<8, false>(ff1_w + (size_t)l * HF * 512, ff1_b + l * HF, xs,
              [&](int b, int r, float val) {
                st_dev(&hff[(size_t)b * HF + r], fmaxf(val, 0.f));
              });
      gsync();

      // ---------- FF2 (blocks 0..63, 8 rows each; K=2048 in two tiles) -----
      if (bid < 64) {
        const int gl = tid & 15, grp = tid >> 4;
        const int r = bid * 8 + grp;
        const bool act = (grp < 8);
        float acc[8] = {0.f, 0.f, 0.f, 0.f, 0.f, 0.f, 0.f, 0.f};
        for (int tl = 0; tl < 2; ++tl) {
          __syncthreads();
          for (int j2 = tid; j2 < 4096; j2 += NTH)   // hff[:, tl*1024..] -> xs
            ((float2*)xs)[j2] = ld_dev2(hff + (size_t)(j2 >> 9) * HF + tl * 1024 + 2 * (j2 & 511));
          __syncthreads();
          if (act) {
            const float4* wr = (const float4*)(ff2_w + ((size_t)l * 512 + r) * HF + (size_t)tl * 1024);
#pragma unroll
            for (int i = 0; i < 16; ++i) {
              const float4 ww = wr[gl + 16 * i];
#pragma unroll
              for (int b2 = 0; b2 < 8; ++b2) {
                const float4 a = ((const float4*)xs)[b2 * 256 + gl + 16 * i];
                acc[b2] = fmaf(ww.x, a.x, acc[b2]);
                acc[b2] = fmaf(ww.y, a.y, acc[b2]);
                acc[b2] = fmaf(ww.z, a.z, acc[b2]);
                acc[b2] = fmaf(ww.w, a.w, acc[b2]);
              }
            }
          }
        }
        if (act) {
#pragma unroll
          for (int b2 = 0; b2 < 8; ++b2) {
            float v = acc[b2];
            v += __shfl_xor(v, 1); v += __shfl_xor(v, 2);
            v += __shfl_xor(v, 4); v += __shfl_xor(v, 8);
            acc[b2] = v;
          }
          if (gl < 8) st_dev(&y2[(size_t)gl * 512 + r], acc[gl] + ff2_b[l * 512 + r]);
        }
      }
      gsync();
    }  // layer loop

    // ---------- final LN3 + logits (approx, fp16 nt) + block candidates ----
    if (w < 8) {
      float v[8];
#pragma unroll
      for (int j2 = 0; j2 < 4; ++j2) {
        const float2 yv = ld_dev2(y2 + (size_t)w * 512 + col0 + 2 * j2);
        v[2 * j2] = x2r[2 * j2] + yv.x;
        v[2 * j2 + 1] = x2r[2 * j2 + 1] + yv.y;
      }
      wave_ln(v, ln3_g + 512, ln3_b + 512);
#pragma unroll
      for (int j = 0; j < 8; ++j) xs[w * 512 + col0 + j] = v[j];
    }
    __syncthreads();
    {
      const int gl = tid & 15, grp = tid >> 4;
      float bestv = -3.4e38f; int besti = 0;
      auto epi = [&](int b, int r, float val) {
        __builtin_nontemporal_store(val, &dlog[((size_t)b * L + t) * V + r]);
        if (val > bestv || (val == bestv && r < besti)) { bestv = val; besti = r; }
      };
      if (use16) {
        for (int i = grp; i < 125; i += NGRP) {
          const int r = bid * 125 + i;
          const u4v* wr = (const u4v*)(w16 + (size_t)r * 512) + gl * 4;
          u4v qs[4];
          qs[0] = __builtin_nontemporal_load(wr);
          qs[1] = __builtin_nontemporal_load(wr + 1);
          qs[2] = __builtin_nontemporal_load(wr + 2);
          qs[3] = __builtin_nontemporal_load(wr + 3);
          float acc[8] = {0.f, 0.f, 0.f, 0.f, 0.f, 0.f, 0.f, 0.f};
#pragma unroll
          for (int m = 0; m < 4; ++m) {
            const __half2* hp = (const __half2*)&qs[m];
            const float2 w0 = __half22float2(hp[0]);
            const float2 w1 = __half22float2(hp[1]);
            const float2 w2 = __half22float2(hp[2]);
            const float2 w3 = __half22float2(hp[3]);
#pragma unroll
            for (int b = 0; b < 8; ++b) {
              const float4* xb = (const float4*)(xs + b * 512);
              const float4 a0 = xb[gl + 32 * m];
              const float4 a1 = xb[gl + 32 * m + 16];
              float s = acc[b];
              s = fmaf(w0.x, a0.x, s); s = fmaf(w0.y, a0.y, s);
              s = fmaf(w1.x, a0.z, s); s = fmaf(w1.y, a0.w, s);
              s = fmaf(w2.x, a1.x, s); s = fmaf(w2.y, a1.y, s);
              s = fmaf(w3.x, a1.z, s); s = fmaf(w3.y, a1.w, s);
              acc[b] = s;
            }
          }
#pragma unroll
          for (int b = 0; b < 8; ++b) {
            float v = acc[b];
            v += __shfl_xor(v, 1); v += __shfl_xor(v, 2);
            v += __shfl_xor(v, 4); v += __shfl_xor(v, 8);
            acc[b] = v;
          }
          if (gl < 8) epi(gl, r, acc[gl] + out_b[r]);
        }
      } else {
        gemv512n<125, true>(out_w, out_b, xs, epi);
      }
      if (gl < 8) gcand[grp * 8 + gl] = make_float2(bestv, (float)besti);
      __syncthreads();
      if (tid < 8) {
        float bv = -3.4e38f, bi = 0.f;
        for (int g2 = 0; g2 < NGRP; ++g2) {
          const float2 cv = gcand[g2 * 8 + tid];
          if (cv.x > bv || (cv.x == bv && cv.y < bi)) { bv = cv.x; bi = cv.y; }
        }
        st_dev2(&cand[((size_t)bid * 8 + tid) * 2], make_float2(bv, bi));
      }
    }
    gsync();

    // ---------- verify: exact argmax of rows within DELTA of approx max ----
    {
      if (w < 8) {  // wave w = batch: global approx max over 256 block bests
        float bv = -3.4e38f;
#pragma unroll
        for (int q = 0; q < 4; ++q) {
          const float2 cv = ld_dev2(&cand[((size_t)(lane + 64 * q) * 8 + w) * 2]);
          bv = fmaxf(bv, cv.x);
        }
#pragma unroll
        for (int m = 1; m < 64; m <<= 1) bv = fmaxf(bv, __shfl_xor(bv, m));
        if (lane == 0) gapx[w] = bv;
      }
      if (tid == 0) qn = 0;
      if (tid < 8)  // clear other-parity slots (consumed >=3 barriers ago)
        __hip_atomic_store(&slot[(size_t)(1 - p) * 8 + tid], 0ull,
                           __ATOMIC_RELAXED, __HIP_MEMORY_SCOPE_AGENT);
      __syncthreads();
      if (tid < 125) {  // scan own 125 rows' approx values
        const int r = bid * 125 + tid;
        for (int b = 0; b < 8; ++b) {
          const float av = dlog[((size_t)b * L + t) * V + r];
          if (av >= gapx[b] - DELTA) {
            const int e = atomicAdd(&qn, 1);
            if (e < 128) qlist[e] = (r << 3) | b;
          }
        }
      }
      __syncthreads();
      const int nq = (qn < 128) ? qn : 128;
      for (int e = w; e < nq; e += 16) {  // wave per flagged (row,batch)
        const int r = qlist[e] >> 3, b = qlist[e] & 7;
        const float* wrow = out_w + (size_t)r * 512 + lane * 8;
        const float4 w0 = ((const float4*)wrow)[0], w1 = ((const float4*)wrow)[1];
        const float* xb = xs + b * 512 + lane * 8;
        float s = 0.f;
        s = fmaf(w0.x, xb[0], s); s = fmaf(w0.y, xb[1], s);
        s = fmaf(w0.z, xb[2], s); s = fmaf(w0.w, xb[3], s);
        s = fmaf(w1.x, xb[4], s); s = fmaf(w1.y, xb[5], s);
        s = fmaf(w1.z, xb[6], s); s = fmaf(w1.w, xb[7], s);
#pragma unroll
        for (int m = 1; m < 64; m <<= 1) s += __shfl_xor(s, m);
        if (lane == 0) {
          const unsigned long long key = packkey(s + out_b[r], r);
          __hip_atomic_fetch_max(&slot[(size_t)p * 8 + b], key,
                                 __ATOMIC_RELAXED, __HIP_MEMORY_SCOPE_AGENT);
        }
      }
    }
    gsync();
  }  // t loop

  // ---------- final token ----------
  if (bid == 0 && tid < 8) {
    const unsigned long long key =
        __hip_atomic_load(&slot[(size_t)((L - 1) & 1) * 8 + tid],
                          __ATOMIC_RELAXED, __HIP_MEMORY_SCOPE_AGENT);
    const int idx = 0x7FFFFFFF - (int)(unsigned)(key & 0xFFFFFFFFull);
    dout[(size_t)tid * L + (L - 1)] = (float)idx;
  }
}

extern "C" void kernel_launch(void* const* d_in, const int* in_sizes, int n_in,
                              void* d_out, int out_size, void* d_ws, size_t ws_size,
                              hipStream_t stream) {
  (void)in_sizes; (void)n_in; (void)out_size;
  (void)hipMemsetAsync(d_ws, 0, 4096, stream);  // barrier flags + argmax slots

  const float* memory    = (const float*)d_in[0];
  const float* embedding = (const float*)d_in[1];
  const float* sa_in_w   = (const float*)d_in[2];
  const float* sa_in_b   = (const float*)d_in[3];
  const float* sa_out_w  = (const float*)d_in[4];
  const float* sa_out_b  = (const float*)d_in[5];
  const float* ca_in_w   = (const float*)d_in[6];
  const float* ca_in_b   = (const float*)d_in[7];
  const float* ca_out_w  = (const float*)d_in[8];
  const float* ca_out_b  = (const float*)d_in[9];
  const float* ff1_w     = (const float*)d_in[10];
  const float* ff1_b     = (const float*)d_in[11];
  const float* ff2_w     = (const float*)d_in[12];
  const float* ff2_b     = (const float*)d_in[13];
  const float* ln1_g     = (const float*)d_in[14];
  const float* ln1_b     = (const float*)d_in[15];
  const float* ln2_g     = (const float*)d_in[16];
  const float* ln2_b     = (const float*)d_in[17];
  const float* ln3_g     = (const float*)d_in[18];
  const float* ln3_b     = (const float*)d_in[19];
  const float* out_w     = (const float*)d_in[20];
  const float* out_b     = (const float*)d_in[21];
  const int*   max_len   = (const int*)d_in[22];

  const int use16 = (ws_size >= cfg::WS_NEED16) ? 1 : 0;

  hipLaunchKernelGGL(decoder_persistent, dim3(NBK), dim3(NTH), 0, stream,
                     memory, embedding, sa_in_w, sa_in_b, sa_out_w, sa_out_b,
                     ca_in_w, ca_in_b, ca_out_w, ca_out_b, ff1_w, ff1_b,
                     ff2_w, ff2_b, ln1_g, ln1_b, ln2_g, ln2_b, ln3_g, ln3_b,
                     out_w, out_b, max_len, (float*)d_out, (float*)d_ws, use16);
}